// Round 3
// baseline (2238.108 us; speedup 1.0000x reference)
//
#include <hip/hip_runtime.h>
#include <cstdint>
#include <cstddef>

#define NG 512        // NUM_GRAPHS
#define NN 131072     // N_NODES
#define NE 4194304    // N_EDGES
#define FIN 54        // F_IN
#define HG 16         // H_GCN
#define HL 32         // H_LSTM
#define NC 192        // N_CLASSES
#define TS 1024       // MAX_SEQ_LEN

__device__ __forceinline__ float rcpf(float x){ return __builtin_amdgcn_rcpf(x); }
__device__ __forceinline__ float sigf(float x){ return rcpf(1.0f + __expf(-x)); }
__device__ __forceinline__ float tanhfast(float x){ return 1.0f - 2.0f*rcpf(__expf(2.0f*x) + 1.0f); }

// repetition macros for named-scalar weight declarations
#define RL1_16(M) M(0) M(1) M(2) M(3) M(4) M(5) M(6) M(7) M(8) M(9) M(10) M(11) M(12) M(13) M(14) M(15)
#define RL1_32(M) RL1_16(M) M(16) M(17) M(18) M(19) M(20) M(21) M(22) M(23) M(24) M(25) M(26) M(27) M(28) M(29) M(30) M(31)
#define RL1_64(M) RL1_32(M) M(32) M(33) M(34) M(35) M(36) M(37) M(38) M(39) M(40) M(41) M(42) M(43) M(44) M(45) M(46) M(47) \
                  M(48) M(49) M(50) M(51) M(52) M(53) M(54) M(55) M(56) M(57) M(58) M(59) M(60) M(61) M(62) M(63)

// quad lists: M(q, 4q, 4q+1, 4q+2, 4q+3)
#define Q4(M)  M(0,0,1,2,3) M(1,4,5,6,7) M(2,8,9,10,11) M(3,12,13,14,15)
#define Q8(M)  Q4(M) M(4,16,17,18,19) M(5,20,21,22,23) M(6,24,25,26,27) M(7,28,29,30,31)
#define Q16(M) Q8(M) M(8,32,33,34,35) M(9,36,37,38,39) M(10,40,41,42,43) M(11,44,45,46,47) \
               M(12,48,49,50,51) M(13,52,53,54,55) M(14,56,57,58,59) M(15,60,61,62,63)

// x-contribution FMAs: xv broadcast float4 from LDS, wa/wb per-lane weights
#define FXQ(q,i0,i1,i2,i3) { float4 xv = x4[q]; \
  a0=fmaf(xv.x,wa##i0,a0); b0=fmaf(xv.x,wb##i0,b0); \
  a1=fmaf(xv.y,wa##i1,a1); b1=fmaf(xv.y,wb##i1,b1); \
  a0=fmaf(xv.z,wa##i2,a0); b0=fmaf(xv.z,wb##i2,b0); \
  a1=fmaf(xv.w,wa##i3,a1); b1=fmaf(xv.w,wb##i3,b1); }
// h-contribution FMAs
#define FHQ(q,i0,i1,i2,i3) { float4 hv4 = h4[q]; \
  a0=fmaf(hv4.x,ua##i0,a0); b0=fmaf(hv4.x,ub##i0,b0); \
  a1=fmaf(hv4.y,ua##i1,a1); b1=fmaf(hv4.y,ub##i1,b1); \
  a0=fmaf(hv4.z,ua##i2,a0); b0=fmaf(hv4.z,ub##i2,b0); \
  a1=fmaf(hv4.w,ua##i3,a1); b1=fmaf(hv4.w,ub##i3,b1); }

// ---------------- init: deg=1 (self loop), counts=0 ----------------
__global__ void k_init(float* __restrict__ deg, int* __restrict__ counts){
  int i = blockIdx.x*256 + threadIdx.x;
  if (i < NN) deg[i] = 1.0f;
  if (i < NG) counts[i] = 0;
}

// ---------------- degree (edges) + per-graph node counts ----------------
__global__ void k_degcnt(const int* __restrict__ ei, const int* __restrict__ batch,
                         float* __restrict__ deg, int* __restrict__ counts){
  int i = blockIdx.x*256 + threadIdx.x;
  if (i < NE) atomicAdd(&deg[ei[NE + i]], 1.0f);
  if (i < NN) atomicAdd(&counts[batch[i]], 1);
}

// ---------------- exclusive scan of counts -> starts (1 block, 512 thr) ----------------
__global__ void k_scan(const int* __restrict__ counts, int* __restrict__ starts){
  __shared__ int sc[NG];
  int t = threadIdx.x;
  sc[t] = counts[t]; __syncthreads();
  for (int off = 1; off < NG; off <<= 1){
    int v = (t >= off) ? sc[t-off] : 0;
    __syncthreads();
    sc[t] += v;
    __syncthreads();
  }
  starts[t] = sc[t] - counts[t];
}

__global__ void k_dinv(const float* __restrict__ deg, float* __restrict__ dinv){
  int i = blockIdx.x*256 + threadIdx.x;
  if (i < NN) dinv[i] = 1.0f / sqrtf(fmaxf(deg[i], 1.0f));
}

// ---------------- xa = x @ w1  (no bias yet) ----------------
__global__ void k_lin1(const float* __restrict__ x, const float* __restrict__ w1,
                       float* __restrict__ xa){
  __shared__ float w[FIN*HG];
  int tid = threadIdx.x;
  for (int i = tid; i < FIN*HG; i += 256) w[i] = w1[i];
  __syncthreads();
  int id = blockIdx.x*256 + tid;
  if (id >= NN*HG) return;
  int node = id >> 4, f = id & 15;
  const float* xr = x + (size_t)node*FIN;
  float acc = 0.0f;
#pragma unroll
  for (int k = 0; k < FIN; k++) acc = fmaf(xr[k], w[k*HG + f], acc);
  xa[id] = acc;
}

// ---------------- agg = v * dinv^2 (self-loop term) ----------------
__global__ void k_selfinit(const float* __restrict__ v, const float* __restrict__ dinv,
                           float* __restrict__ agg){
  int id = blockIdx.x*256 + threadIdx.x;
  if (id >= NN*HG) return;
  float di = dinv[id >> 4];
  agg[id] = v[id] * di * di;
}

// ---------------- agg[dst] += v[src]*dinv[src]*dinv[dst] over edges ----------------
__global__ void k_scatter(const int* __restrict__ ei, const float* __restrict__ v,
                          const float* __restrict__ dinv, float* __restrict__ agg){
  int id = blockIdx.x*256 + threadIdx.x;
  if (id >= NE*HG) return;
  int e = id >> 4, f = id & 15;
  int s = ei[e], d = ei[NE + e];
  float nv = dinv[s] * dinv[d];
  atomicAdd(&agg[d*HG + f], v[s*HG + f] * nv);
}

// ---------------- hb = relu(agg + b1) @ w2 ----------------
__global__ void k_relu_lin(const float* __restrict__ agg, const float* __restrict__ b1,
                           const float* __restrict__ w2, float* __restrict__ hb){
  __shared__ float w[HG*HG];
  __shared__ float bb[HG];
  int tid = threadIdx.x;
  if (tid < HG*HG) w[tid] = w2[tid];
  if (tid < HG) bb[tid] = b1[tid];
  __syncthreads();
  int id = blockIdx.x*256 + tid;
  if (id >= NN*HG) return;
  int node = id >> 4, f = id & 15;
  const float* ar = agg + (size_t)node*HG;
  float acc = 0.0f;
#pragma unroll
  for (int k = 0; k < HG; k++){
    float h = fmaxf(ar[k] + bb[k], 0.0f);
    acc = fmaf(h, w[k*HG + f], acc);
  }
  hb[id] = acc;
}

// ---------------- h2 = relu(agg + b2) ----------------
__global__ void k_relu(const float* __restrict__ agg, const float* __restrict__ b2,
                       float* __restrict__ h2){
  int id = blockIdx.x*256 + threadIdx.x;
  if (id >= NN*HG) return;
  h2[id] = fmaxf(agg[id] + b2[id & 15], 0.0f);
}

// ---------------- BiLSTM layer 0: one wave per (graph, dir) ----------------
// Broadcasts via LDS ds_read_b128 (same-address = free broadcast); no barriers
// (single wave, per-wave DS ordering). x double-buffered in distinct arrays so
// next-x ds_write doesn't alias-serialize against current-x ds_reads.
__global__ __launch_bounds__(64, 1) void k_lstm0(
    const float* __restrict__ h2in, const int* __restrict__ starts, const int* __restrict__ counts,
    const float* __restrict__ wih, const float* __restrict__ whh,
    const float* __restrict__ bih, const float* __restrict__ bhh,
    float* __restrict__ out0)
{
  const int g = blockIdx.x >> 1, dir = blockIdx.x & 1;
  const int lane = threadIdx.x;
  const int j = lane & 31, half = lane >> 5;
  const int gA = half*32 + j, gB = 64 + half*32 + j;
  const float* wihd = wih + (size_t)dir*128*HG;
  const float* whhd = whh + (size_t)dir*128*HL;
#define DWA0(i) float wa##i = wihd[gA*HG + i];
#define DWB0(i) float wb##i = wihd[gB*HG + i];
#define DUA0(i) float ua##i = whhd[gA*HL + i];
#define DUB0(i) float ub##i = whhd[gB*HL + i];
  RL1_16(DWA0) RL1_16(DWB0) RL1_32(DUA0) RL1_32(DUB0)
  const float pbA = bih[dir*128 + gA] + bhh[dir*128 + gA];
  const float pbB = bih[dir*128 + gB] + bhh[dir*128 + gB];
  int cnt = counts[g]; if (cnt > TS) cnt = TS;
  const int s0 = starts[g];
  float* outg = out0 + (size_t)g*TS*64 + dir*32;

  __shared__ __align__(16) float xb0[HG], xb1[HG], hb[HL];

  // backward dir: with all-zero effective biases, zero input keeps state exactly 0,
  // so steps t >= cnt produce h == 0. Guard with a runtime bias check.
  unsigned long long zb = __ballot(pbA == 0.0f && pbB == 0.0f);
  bool allzero = (zb == ~0ull);

  int t0, dt, nst;
  if (dir == 0){ t0 = 0; dt = 1; nst = TS; }
  else if (allzero){
    for (int t = cnt; t < TS; ++t) if (half) outg[(size_t)t*64 + j] = 0.0f;
    t0 = cnt - 1; dt = -1; nst = cnt;
  } else { t0 = TS - 1; dt = -1; nst = TS; }

  float xv0 = 0.0f;
  if (lane < HG && nst > 0 && (unsigned)t0 < (unsigned)cnt)
    xv0 = h2in[(size_t)(s0 + t0)*HG + lane];
  if (lane < HG) xb0[lane] = xv0;
  if (lane < HL) hb[lane] = 0.0f;
  float c = 0.0f;

#define STEP0(XC, XN, T) { \
    int tnx = (T) + dt; \
    float xnreg = 0.0f; \
    if (lane < HG && (unsigned)tnx < (unsigned)cnt) \
      xnreg = h2in[(size_t)(s0 + tnx)*HG + lane]; \
    float a0 = pbA, a1 = 0.0f, b0 = pbB, b1 = 0.0f; \
    if ((T) < cnt){ const float4* x4 = (const float4*)(XC); Q4(FXQ) } \
    { const float4* h4 = (const float4*)hb; Q8(FHQ) } \
    if (lane < HG) (XN)[lane] = xnreg; \
    float aA = a0 + a1, aB = b0 + b1; \
    float sA = sigf(aA); \
    float u  = half ? aB : (aB + aB); \
    float sB = rcpf(1.0f + __expf(-u)); \
    float vB = half ? sB : (sB + sB - 1.0f); \
    float p  = sA * vB; \
    float pj = __shfl(p, j); \
    c = fmaf(sA, c, pj); \
    float hv = vB * tanhfast(c); \
    if (half){ hb[j] = hv; outg[(size_t)(T)*64 + j] = hv; } \
  }

  int tt = 0;
  for (; tt + 2 <= nst; tt += 2){
    int t = t0 + tt*dt;
    STEP0(xb0, xb1, t)
    STEP0(xb1, xb0, t + dt)
  }
  if (tt < nst){ int t = t0 + tt*dt; STEP0(xb0, xb1, t) }
}

// ---------------- BiLSTM layer 1 + mean pooling ----------------
__global__ __launch_bounds__(64, 1) void k_lstm1(
    const float* __restrict__ gl0, const float* __restrict__ wih, const float* __restrict__ whh,
    const float* __restrict__ bih, const float* __restrict__ bhh,
    float* __restrict__ pooled)
{
  const int g = blockIdx.x >> 1, dir = blockIdx.x & 1;
  const int lane = threadIdx.x;
  const int j = lane & 31, half = lane >> 5;
  const int gA = half*32 + j, gB = 64 + half*32 + j;
  const float* wihd = wih + (size_t)dir*128*64;
  const float* whhd = whh + (size_t)dir*128*HL;
#define DWA1(i) float wa##i = wihd[gA*64 + i];
#define DWB1(i) float wb##i = wihd[gB*64 + i];
#define DUA1(i) float ua##i = whhd[gA*HL + i];
#define DUB1(i) float ub##i = whhd[gB*HL + i];
  RL1_64(DWA1) RL1_64(DWB1) RL1_32(DUA1) RL1_32(DUB1)
  const float pbA = bih[dir*128 + gA] + bhh[dir*128 + gA];
  const float pbB = bih[dir*128 + gB] + bhh[dir*128 + gB];
  const float* gin = gl0 + (size_t)g*TS*64;

  __shared__ __align__(16) float xb0[64], xb1[64], hb[HL];

  const int t0 = dir ? (TS - 1) : 0, dt = dir ? -1 : 1;
  xb0[lane] = gin[(size_t)t0*64 + lane];
  if (lane < HL) hb[lane] = 0.0f;
  float c = 0.0f, hsum = 0.0f;

#define STEP1(XC, XN, T) { \
    int tnx = (T) + dt; \
    float xnreg = 0.0f; \
    if ((unsigned)tnx < TS) xnreg = gin[(size_t)tnx*64 + lane]; \
    float a0 = pbA, a1 = 0.0f, b0 = pbB, b1 = 0.0f; \
    { const float4* x4 = (const float4*)(XC); Q16(FXQ) } \
    { const float4* h4 = (const float4*)hb; Q8(FHQ) } \
    (XN)[lane] = xnreg; \
    float aA = a0 + a1, aB = b0 + b1; \
    float sA = sigf(aA); \
    float u  = half ? aB : (aB + aB); \
    float sB = rcpf(1.0f + __expf(-u)); \
    float vB = half ? sB : (sB + sB - 1.0f); \
    float p  = sA * vB; \
    float pj = __shfl(p, j); \
    c = fmaf(sA, c, pj); \
    float hv = vB * tanhfast(c); \
    if (half){ hb[j] = hv; hsum += hv; } \
  }

  for (int tt = 0; tt < TS; tt += 2){
    int t = t0 + tt*dt;
    STEP1(xb0, xb1, t)
    STEP1(xb1, xb0, t + dt)
  }
  if (half) pooled[(size_t)g*64 + dir*32 + j] = hsum * (1.0f/(float)TS);
}

// ---------------- FC: out = pooled @ fc_w + fc_b ----------------
__global__ void k_fc(const float* __restrict__ pooled, const float* __restrict__ fcw,
                     const float* __restrict__ fcb, float* __restrict__ out){
  __shared__ float p[64];
  int g = blockIdx.x, cix = threadIdx.x;
  if (cix < 64) p[cix] = pooled[(size_t)g*64 + cix];
  __syncthreads();
  float acc = fcb[cix];
#pragma unroll
  for (int k = 0; k < 64; k++) acc = fmaf(p[k], fcw[k*NC + cix], acc);
  out[(size_t)g*NC + cix] = acc;
}

extern "C" void kernel_launch(void* const* d_in, const int* in_sizes, int n_in,
                              void* d_out, int out_size, void* d_ws, size_t ws_size,
                              hipStream_t stream) {
  const float* x        = (const float*)d_in[0];
  const int*   ei       = (const int*)  d_in[1];
  const int*   batch    = (const int*)  d_in[2];
  const float* gcn_w1   = (const float*)d_in[3];
  const float* gcn_b1   = (const float*)d_in[4];
  const float* gcn_w2   = (const float*)d_in[5];
  const float* gcn_b2   = (const float*)d_in[6];
  const float* l0_wih   = (const float*)d_in[7];
  const float* l0_whh   = (const float*)d_in[8];
  const float* l0_bih   = (const float*)d_in[9];
  const float* l0_bhh   = (const float*)d_in[10];
  const float* l1_wih   = (const float*)d_in[11];
  const float* l1_whh   = (const float*)d_in[12];
  const float* l1_bih   = (const float*)d_in[13];
  const float* l1_bhh   = (const float*)d_in[14];
  const float* fc_w     = (const float*)d_in[15];
  const float* fc_b     = (const float*)d_in[16];
  float* out = (float*)d_out;

  // workspace layout (floats)
  float* ws   = (float*)d_ws;
  float* B0   = ws;                    // N*16 : xa -> agg2
  float* B1   = B0 + (size_t)NN*HG;    // N*16 : agg1 -> h2
  float* B2   = B1 + (size_t)NN*HG;    // N*16 : hb
  float* deg  = B2 + (size_t)NN*HG;    // N
  float* dinv = deg + NN;              // N
  int*   counts = (int*)(dinv + NN);   // 512
  int*   starts = counts + NG;         // 512
  float* pooled = (float*)(starts + NG);      // 512*64
  float* out0   = pooled + (size_t)NG*64;     // 512*1024*64
  size_t needed = ((size_t)(out0 - ws) + (size_t)NG*TS*64) * sizeof(float);
  if (ws_size < needed) return;  // fail loudly (poisoned d_out) rather than corrupt

  k_init   <<<(NN+255)/256, 256, 0, stream>>>(deg, counts);
  k_degcnt <<<(NE+255)/256, 256, 0, stream>>>(ei, batch, deg, counts);
  k_scan   <<<1, NG, 0, stream>>>(counts, starts);
  k_dinv   <<<(NN+255)/256, 256, 0, stream>>>(deg, dinv);
  k_lin1   <<<(NN*HG)/256, 256, 0, stream>>>(x, gcn_w1, B0);
  k_selfinit<<<(NN*HG)/256, 256, 0, stream>>>(B0, dinv, B1);
  k_scatter<<<(NE*HG)/256, 256, 0, stream>>>(ei, B0, dinv, B1);
  k_relu_lin<<<(NN*HG)/256, 256, 0, stream>>>(B1, gcn_b1, gcn_w2, B2);
  k_selfinit<<<(NN*HG)/256, 256, 0, stream>>>(B2, dinv, B0);
  k_scatter<<<(NE*HG)/256, 256, 0, stream>>>(ei, B2, dinv, B0);
  k_relu   <<<(NN*HG)/256, 256, 0, stream>>>(B0, gcn_b2, B1);
  k_lstm0  <<<NG*2, 64, 0, stream>>>(B1, starts, counts, l0_wih, l0_whh, l0_bih, l0_bhh, out0);
  k_lstm1  <<<NG*2, 64, 0, stream>>>(out0, l1_wih, l1_whh, l1_bih, l1_bhh, pooled);
  k_fc     <<<NG, NC, 0, stream>>>(pooled, fc_w, fc_b, out);
}

// Round 4
// 1661.225 us; speedup vs baseline: 1.3473x; 1.3473x over previous
//
#include <hip/hip_runtime.h>
#include <cstdint>
#include <cstddef>

#define NG 512        // NUM_GRAPHS
#define NN 131072     // N_NODES
#define NE 4194304    // N_EDGES
#define FIN 54        // F_IN
#define HG 16         // H_GCN
#define HL 32         // H_LSTM
#define NC 192        // N_CLASSES
#define TS 1024       // MAX_SEQ_LEN

__device__ __forceinline__ float rcpf(float x){ return __builtin_amdgcn_rcpf(x); }
__device__ __forceinline__ float sigf(float x){ return rcpf(1.0f + __expf(-x)); }
__device__ __forceinline__ float tanhfast(float x){ return 1.0f - 2.0f*rcpf(__expf(2.0f*x) + 1.0f); }

// ---------------- init: deg=1 (self loop), counts=0 ----------------
__global__ void k_init(float* __restrict__ deg, int* __restrict__ counts){
  int i = blockIdx.x*256 + threadIdx.x;
  if (i < NN) deg[i] = 1.0f;
  if (i < NG) counts[i] = 0;
}

// ---------------- degree (edges) + per-graph node counts ----------------
__global__ void k_degcnt(const int* __restrict__ ei, const int* __restrict__ batch,
                         float* __restrict__ deg, int* __restrict__ counts){
  int i = blockIdx.x*256 + threadIdx.x;
  if (i < NE) atomicAdd(&deg[ei[NE + i]], 1.0f);
  if (i < NN) atomicAdd(&counts[batch[i]], 1);
}

// ---------------- exclusive scan of counts -> starts (1 block, 512 thr) ----------------
__global__ void k_scan(const int* __restrict__ counts, int* __restrict__ starts){
  __shared__ int sc[NG];
  int t = threadIdx.x;
  sc[t] = counts[t]; __syncthreads();
  for (int off = 1; off < NG; off <<= 1){
    int v = (t >= off) ? sc[t-off] : 0;
    __syncthreads();
    sc[t] += v;
    __syncthreads();
  }
  starts[t] = sc[t] - counts[t];
}

__global__ void k_dinv(const float* __restrict__ deg, float* __restrict__ dinv){
  int i = blockIdx.x*256 + threadIdx.x;
  if (i < NN) dinv[i] = 1.0f / sqrtf(fmaxf(deg[i], 1.0f));
}

// ---------------- xa = x @ w1  (no bias yet) ----------------
__global__ void k_lin1(const float* __restrict__ x, const float* __restrict__ w1,
                       float* __restrict__ xa){
  __shared__ float w[FIN*HG];
  int tid = threadIdx.x;
  for (int i = tid; i < FIN*HG; i += 256) w[i] = w1[i];
  __syncthreads();
  int id = blockIdx.x*256 + tid;
  if (id >= NN*HG) return;
  int node = id >> 4, f = id & 15;
  const float* xr = x + (size_t)node*FIN;
  float acc = 0.0f;
#pragma unroll
  for (int k = 0; k < FIN; k++) acc = fmaf(xr[k], w[k*HG + f], acc);
  xa[id] = acc;
}

// ---------------- agg = v * dinv^2 (self-loop term) ----------------
__global__ void k_selfinit(const float* __restrict__ v, const float* __restrict__ dinv,
                           float* __restrict__ agg){
  int id = blockIdx.x*256 + threadIdx.x;
  if (id >= NN*HG) return;
  float di = dinv[id >> 4];
  agg[id] = v[id] * di * di;
}

// ---------------- agg[dst] += v[src]*dinv[src]*dinv[dst] over edges ----------------
__global__ void k_scatter(const int* __restrict__ ei, const float* __restrict__ v,
                          const float* __restrict__ dinv, float* __restrict__ agg){
  int id = blockIdx.x*256 + threadIdx.x;
  if (id >= NE*HG) return;
  int e = id >> 4, f = id & 15;
  int s = ei[e], d = ei[NE + e];
  float nv = dinv[s] * dinv[d];
  atomicAdd(&agg[d*HG + f], v[s*HG + f] * nv);
}

// ---------------- hb = relu(agg + b1) @ w2 ----------------
__global__ void k_relu_lin(const float* __restrict__ agg, const float* __restrict__ b1,
                           const float* __restrict__ w2, float* __restrict__ hb){
  __shared__ float w[HG*HG];
  __shared__ float bb[HG];
  int tid = threadIdx.x;
  if (tid < HG*HG) w[tid] = w2[tid];
  if (tid < HG) bb[tid] = b1[tid];
  __syncthreads();
  int id = blockIdx.x*256 + tid;
  if (id >= NN*HG) return;
  int node = id >> 4, f = id & 15;
  const float* ar = agg + (size_t)node*HG;
  float acc = 0.0f;
#pragma unroll
  for (int k = 0; k < HG; k++){
    float h = fmaxf(ar[k] + bb[k], 0.0f);
    acc = fmaf(h, w[k*HG + f], acc);
  }
  hb[id] = acc;
}

// ---------------- h2 = relu(agg + b2) ----------------
__global__ void k_relu(const float* __restrict__ agg, const float* __restrict__ b2,
                       float* __restrict__ h2){
  int id = blockIdx.x*256 + threadIdx.x;
  if (id >= NN*HG) return;
  h2[id] = fmaxf(agg[id] + b2[id & 15], 0.0f);
}

// ============ BiLSTM: 2 waves per (graph,dir), ONE gate row per lane ============
// Thread map: wv=tid>>6, lane=tid&63, sub=lane&31, hi=lane>>5.
// wave0: i (lanes 0-31, row sub), g (lanes 32-63, row 64+sub)
// wave1: f (lanes 0-31, row 32+sub) owns c; o (lanes 32-63, row 96+sub) owns h.
// Per step: all compute gate preact from LDS-broadcast x,h; wave0 makes
// p = sig(i)*tanh(g) -> pbuf; barrier; wave1 updates c,h -> hbuf[nxt]; detects
// bitwise fixed point (valid when input is in its constant region); barrier.

// ---------------- layer 0 ----------------
__global__ __launch_bounds__(128, 2) void k_lstm0(
    const float* __restrict__ h2in, const int* __restrict__ starts, const int* __restrict__ counts,
    const float* __restrict__ wih, const float* __restrict__ whh,
    const float* __restrict__ bih, const float* __restrict__ bhh,
    float* __restrict__ out0, int* __restrict__ tconv)
{
  const int g = blockIdx.x >> 1, dir = blockIdx.x & 1;
  const int tid = threadIdx.x;
  const int wv = tid >> 6, lane = tid & 63;
  const int sub = lane & 31, hi = lane >> 5;
  const int r = wv ? (hi ? 96 + sub : 32 + sub) : (hi ? 64 + sub : sub);
  const float* wihd = wih + (size_t)dir*128*HG + (size_t)r*HG;
  const float* whhd = whh + (size_t)dir*128*HL + (size_t)r*HL;
  float wr[HG], ur[HL];
#pragma unroll
  for (int k = 0; k < HG; k++) wr[k] = wihd[k];
#pragma unroll
  for (int k = 0; k < HL; k++) ur[k] = whhd[k];
  const float pb = bih[dir*128 + r] + bhh[dir*128 + r];
  int cnt = counts[g]; if (cnt > TS) cnt = TS;
  const int s0 = starts[g];
  float* outg = out0 + (size_t)g*TS*64 + dir*32;

  __shared__ __align__(16) float xs[2][HG];
  __shared__ __align__(16) float hbuf[2][HL];
  __shared__ __align__(16) float pbuf[HL];
  __shared__ int flagbuf[2];
  __shared__ unsigned long long azm[2];

  unsigned long long bz = __ballot(pb == 0.0f);
  if (lane == 0) azm[wv] = bz;
  if (tid < HL) hbuf[0][tid] = 0.0f;
  if (tid < 2) flagbuf[tid] = 0;
  __syncthreads();
  bool allzero = (azm[0] == ~0ull) && (azm[1] == ~0ull);

  int t0, dt;
  bool skipall = false;
  if (dir == 0){ t0 = 0; dt = 1; }
  else {
    if (allzero){
      // zero bias + zero input keeps state exactly 0 -> rows >= cnt are 0
      for (int rr = cnt + (tid >> 5); rr < TS; rr += 4) outg[(size_t)rr*64 + sub] = 0.0f;
      t0 = cnt - 1; dt = -1;
      if (t0 < 0) skipall = true;
    } else { t0 = TS - 1; dt = -1; }
  }

  float xB = 0.0f, xC = 0.0f;
  if (!skipall && wv == 0){
    float xA = 0.0f;
    if (t0 >= 0 && t0 < cnt && lane < HG)      xA = h2in[(size_t)(s0 + t0)*HG + lane];
    int tb = t0 + dt;
    if (tb >= 0 && tb < cnt && lane < HG)      xB = h2in[(size_t)(s0 + tb)*HG + lane];
    int tc2 = t0 + 2*dt;
    if (tc2 >= 0 && tc2 < cnt && lane < HG)    xC = h2in[(size_t)(s0 + tc2)*HG + lane];
    if (lane < HG) xs[0][lane] = xA;
  }
  __syncthreads();

  int t = t0, cur = 0;
  float c = 0.0f, h = 0.0f;
  bool convdone = false;

  if (!skipall)
  for (;;){
    int nxt = cur ^ 1;
    float xD = 0.0f;
    {
      int tp = t + 3*dt;
      if (wv == 0 && tp >= 0 && tp < cnt && lane < HG) xD = h2in[(size_t)(s0 + tp)*HG + lane];
    }
    float a0 = pb, a1 = 0.0f, a2 = 0.0f, a3 = 0.0f;
    const float4* x4 = (const float4*)xs[cur];
    const float4* h4 = (const float4*)hbuf[cur];
#pragma unroll
    for (int q = 0; q < HG/4; q++){ float4 xv = x4[q];
      a0 = fmaf(xv.x, wr[4*q+0], a0); a1 = fmaf(xv.y, wr[4*q+1], a1);
      a2 = fmaf(xv.z, wr[4*q+2], a2); a3 = fmaf(xv.w, wr[4*q+3], a3); }
#pragma unroll
    for (int q = 0; q < HL/4; q++){ float4 hv = h4[q];
      a0 = fmaf(hv.x, ur[4*q+0], a0); a1 = fmaf(hv.y, ur[4*q+1], a1);
      a2 = fmaf(hv.z, ur[4*q+2], a2); a3 = fmaf(hv.w, ur[4*q+3], a3); }
    float a = (a0 + a1) + (a2 + a3);
    if (wv == 0 && lane < HG) xs[nxt][lane] = xB;
    float sv1 = 0.0f;
    if (wv == 0){
      float u  = hi ? (a + a) : a;
      float sv = sigf(u);
      float v  = hi ? (sv + sv - 1.0f) : sv;   // hi: tanh(g); lo: sig(i)
      float gv = __shfl(v, 32 + sub);
      float p  = v * gv;                        // valid on lo lanes
      if (lane < HL) pbuf[lane] = p;
    } else {
      sv1 = sigf(a);                            // f or o
    }
    __syncthreads();  // barrier1: pbuf, xs[nxt] visible
    if (wv == 1){
      float cn = 0.0f, tcn = 0.0f;
      if (!hi){ cn = fmaf(sv1, c, pbuf[sub]); tcn = tanhfast(cn); }
      float tcs = __shfl(tcn, sub);
      bool eq;
      if (!hi){ eq = (cn == c); c = cn; }
      else {
        float hn = sv1 * tcs;
        eq = (hn == h); h = hn;
        hbuf[nxt][sub] = h;
        outg[(size_t)t*64 + sub] = h;
      }
      unsigned long long m = __ballot(eq);
      bool conv = (m == ~0ull) && (dir == 0) && (t >= cnt + 1);
      if (lane == 32) flagbuf[nxt] = conv ? 1 : 0;
    }
    __syncthreads();  // barrier2: hbuf[nxt], flag visible
    int fl = flagbuf[nxt];
    if (fl){
      // state fixed under constant (zero) input: all remaining rows equal h*
      float hval = hbuf[nxt][sub];
      for (int rr = t + 1 + (tid >> 5); rr < TS; rr += 4) outg[(size_t)rr*64 + sub] = hval;
      if (tid == 96) tconv[g] = t - 1;   // rows t-1.. are bitwise constant
      convdone = true;
      break;
    }
    t += dt;
    if (dir == 0){ if (t >= TS) break; } else { if (t < 0) break; }
    xB = xC; xC = xD; cur = nxt;
  }
  if (dir == 0 && !convdone && tid == 96) tconv[g] = TS;
}

// ---------------- layer 1 + mean pool ----------------
__global__ __launch_bounds__(128, 2) void k_lstm1(
    const float* __restrict__ gl0, const int* __restrict__ tconv,
    const float* __restrict__ wih, const float* __restrict__ whh,
    const float* __restrict__ bih, const float* __restrict__ bhh,
    float* __restrict__ pooled)
{
  const int g = blockIdx.x >> 1, dir = blockIdx.x & 1;
  const int tid = threadIdx.x;
  const int wv = tid >> 6, lane = tid & 63;
  const int sub = lane & 31, hi = lane >> 5;
  const int r = wv ? (hi ? 96 + sub : 32 + sub) : (hi ? 64 + sub : sub);
  const float* wihd = wih + (size_t)dir*128*64 + (size_t)r*64;
  const float* whhd = whh + (size_t)dir*128*HL + (size_t)r*HL;
  float wr[64], ur[HL];
#pragma unroll
  for (int k = 0; k < 64; k++) wr[k] = wihd[k];
#pragma unroll
  for (int k = 0; k < HL; k++) ur[k] = whhd[k];
  const float pb = bih[dir*128 + r] + bhh[dir*128 + r];
  const float* gin = gl0 + (size_t)g*TS*64;
  const int tcv = tconv[g];

  __shared__ __align__(16) float xs[2][64];
  __shared__ __align__(16) float hbuf[2][HL];
  __shared__ __align__(16) float pbuf[HL];
  __shared__ int flagbuf[2];

  if (tid < HL) hbuf[0][tid] = 0.0f;
  if (tid < 2) flagbuf[tid] = 0;

  const int t0 = dir ? (TS - 1) : 0, dt = dir ? -1 : 1;
#define LD1(tt) gin[(size_t)((tt) < 0 ? 0 : ((tt) > TS-1 ? TS-1 : (tt)))*64 + lane]
  float xB = 0.0f, xC = 0.0f;
  if (wv == 0){
    float xA = LD1(t0);
    xB = LD1(t0 + dt);
    xC = LD1(t0 + 2*dt);
    xs[0][lane] = xA;
  }
  __syncthreads();

  int t = t0, cur = 0;
  float c = 0.0f, h = 0.0f, hsum = 0.0f;

  for (;;){
    int nxt = cur ^ 1;
    float xD = 0.0f;
    if (wv == 0) xD = LD1(t + 3*dt);
    float a0 = pb, a1 = 0.0f, a2 = 0.0f, a3 = 0.0f;
    const float4* x4 = (const float4*)xs[cur];
    const float4* h4 = (const float4*)hbuf[cur];
#pragma unroll
    for (int q = 0; q < 16; q++){ float4 xv = x4[q];
      a0 = fmaf(xv.x, wr[4*q+0], a0); a1 = fmaf(xv.y, wr[4*q+1], a1);
      a2 = fmaf(xv.z, wr[4*q+2], a2); a3 = fmaf(xv.w, wr[4*q+3], a3); }
#pragma unroll
    for (int q = 0; q < HL/4; q++){ float4 hv = h4[q];
      a0 = fmaf(hv.x, ur[4*q+0], a0); a1 = fmaf(hv.y, ur[4*q+1], a1);
      a2 = fmaf(hv.z, ur[4*q+2], a2); a3 = fmaf(hv.w, ur[4*q+3], a3); }
    float a = (a0 + a1) + (a2 + a3);
    if (wv == 0) xs[nxt][lane] = xB;
    float sv1 = 0.0f;
    if (wv == 0){
      float u  = hi ? (a + a) : a;
      float sv = sigf(u);
      float v  = hi ? (sv + sv - 1.0f) : sv;
      float gv = __shfl(v, 32 + sub);
      float p  = v * gv;
      if (lane < HL) pbuf[lane] = p;
    } else {
      sv1 = sigf(a);
    }
    __syncthreads();  // barrier1
    if (wv == 1){
      float cn = 0.0f, tcn = 0.0f;
      if (!hi){ cn = fmaf(sv1, c, pbuf[sub]); tcn = tanhfast(cn); }
      float tcs = __shfl(tcn, sub);
      bool eq;
      if (!hi){ eq = (cn == c); c = cn; }
      else {
        float hn = sv1 * tcs;
        eq = (hn == h); h = hn;
        hsum += h;
        hbuf[nxt][sub] = h;
      }
      unsigned long long m = __ballot(eq);
      bool conv = (m == ~0ull) && (t >= tcv + 1);
      if (lane == 32) flagbuf[nxt] = conv ? 1 : 0;
    }
    __syncthreads();  // barrier2
    int fl = flagbuf[nxt];
    if (fl){
      if (dir == 0){
        // x constant for all remaining t; state fixed -> close the mean
        if (wv == 1 && hi) hsum += h * (float)(TS - 1 - t);
        break;
      } else {
        // rows [tcv, t-1] all equal current x; state fixed -> h* repeats
        if (wv == 1 && hi) hsum += h * (float)(t - tcv);
        t = tcv - 1;
        if (t < 0) break;
        if (wv == 0){
          float xA = LD1(t);
          xs[nxt][lane] = xA;       // overwrite with row t
          xB = LD1(t - 1);
          xC = LD1(t - 2);
        }
        __syncthreads();            // re-prime barrier
        cur = nxt;
        continue;
      }
    }
    t += dt;
    if (dir == 0){ if (t >= TS) break; } else { if (t < 0) break; }
    xB = xC; xC = xD; cur = nxt;
  }
  if (wv == 1 && hi) pooled[(size_t)g*64 + dir*32 + sub] = hsum * (1.0f/(float)TS);
#undef LD1
}

// ---------------- FC: out = pooled @ fc_w + fc_b ----------------
__global__ void k_fc(const float* __restrict__ pooled, const float* __restrict__ fcw,
                     const float* __restrict__ fcb, float* __restrict__ out){
  __shared__ float p[64];
  int g = blockIdx.x, cix = threadIdx.x;
  if (cix < 64) p[cix] = pooled[(size_t)g*64 + cix];
  __syncthreads();
  float acc = fcb[cix];
#pragma unroll
  for (int k = 0; k < 64; k++) acc = fmaf(p[k], fcw[k*NC + cix], acc);
  out[(size_t)g*NC + cix] = acc;
}

extern "C" void kernel_launch(void* const* d_in, const int* in_sizes, int n_in,
                              void* d_out, int out_size, void* d_ws, size_t ws_size,
                              hipStream_t stream) {
  const float* x        = (const float*)d_in[0];
  const int*   ei       = (const int*)  d_in[1];
  const int*   batch    = (const int*)  d_in[2];
  const float* gcn_w1   = (const float*)d_in[3];
  const float* gcn_b1   = (const float*)d_in[4];
  const float* gcn_w2   = (const float*)d_in[5];
  const float* gcn_b2   = (const float*)d_in[6];
  const float* l0_wih   = (const float*)d_in[7];
  const float* l0_whh   = (const float*)d_in[8];
  const float* l0_bih   = (const float*)d_in[9];
  const float* l0_bhh   = (const float*)d_in[10];
  const float* l1_wih   = (const float*)d_in[11];
  const float* l1_whh   = (const float*)d_in[12];
  const float* l1_bih   = (const float*)d_in[13];
  const float* l1_bhh   = (const float*)d_in[14];
  const float* fc_w     = (const float*)d_in[15];
  const float* fc_b     = (const float*)d_in[16];
  float* out = (float*)d_out;

  // workspace layout (floats)
  float* ws   = (float*)d_ws;
  float* B0   = ws;                    // N*16 : xa -> agg2
  float* B1   = B0 + (size_t)NN*HG;    // N*16 : agg1 -> h2
  float* B2   = B1 + (size_t)NN*HG;    // N*16 : hb
  float* deg  = B2 + (size_t)NN*HG;    // N
  float* dinv = deg + NN;              // N
  int*   counts = (int*)(dinv + NN);   // 512
  int*   starts = counts + NG;         // 512
  int*   tconv  = starts + NG;         // 512
  float* pooled = (float*)(tconv + NG);       // 512*64
  float* out0   = pooled + (size_t)NG*64;     // 512*1024*64
  size_t needed = ((size_t)(out0 - ws) + (size_t)NG*TS*64) * sizeof(float);
  if (ws_size < needed) return;  // fail loudly (poisoned d_out) rather than corrupt

  k_init   <<<(NN+255)/256, 256, 0, stream>>>(deg, counts);
  k_degcnt <<<(NE+255)/256, 256, 0, stream>>>(ei, batch, deg, counts);
  k_scan   <<<1, NG, 0, stream>>>(counts, starts);
  k_dinv   <<<(NN+255)/256, 256, 0, stream>>>(deg, dinv);
  k_lin1   <<<(NN*HG)/256, 256, 0, stream>>>(x, gcn_w1, B0);
  k_selfinit<<<(NN*HG)/256, 256, 0, stream>>>(B0, dinv, B1);
  k_scatter<<<(NE*HG)/256, 256, 0, stream>>>(ei, B0, dinv, B1);
  k_relu_lin<<<(NN*HG)/256, 256, 0, stream>>>(B1, gcn_b1, gcn_w2, B2);
  k_selfinit<<<(NN*HG)/256, 256, 0, stream>>>(B2, dinv, B0);
  k_scatter<<<(NE*HG)/256, 256, 0, stream>>>(ei, B2, dinv, B0);
  k_relu   <<<(NN*HG)/256, 256, 0, stream>>>(B0, gcn_b2, B1);
  k_lstm0  <<<NG*2, 128, 0, stream>>>(B1, starts, counts, l0_wih, l0_whh, l0_bih, l0_bhh, out0, tconv);
  k_lstm1  <<<NG*2, 128, 0, stream>>>(out0, tconv, l1_wih, l1_whh, l1_bih, l1_bhh, pooled);
  k_fc     <<<NG, NC, 0, stream>>>(pooled, fc_w, fc_b, out);
}